// Round 1
// baseline (235.013 us; speedup 1.0000x reference)
//
#include <hip/hip_runtime.h>
#include <hip/hip_bf16.h>
#include <math.h>

// SegmentGatingNetwork: x[T,1024] -> h=tanh(x@W1+b1)[T,256] -> logits=h@W2+b2[T,64]
// -> top-2 softmax scatter -> gates[T,64]. Outputs: gates then logits in d_out.
// T = 16384. All fp32.

#define DM 1024
#define DH 256
#define NE 64

// ---------------- GEMM1: h = tanh(x @ W1 + b1) ----------------
// tile: 64 tokens x 128 hidden, TK=16. block=256 threads, 8tok x 4hid per thread.
// grid: (T/64, 2)
__global__ __launch_bounds__(256, 2)
void gemm1_kernel(const float* __restrict__ x, const float* __restrict__ W1,
                  const float* __restrict__ b1, float* __restrict__ h) {
    __shared__ float xs[16][68];   // xs[k][tok], pad 68 (16B-aligned rows, 2-way banks = free)
    __shared__ float ws[16][128];  // ws[k][n]

    const int tid = threadIdx.x;
    const int t0 = blockIdx.x * 64;
    const int n0 = blockIdx.y * 128;
    const int tx = tid & 31;   // hidden group: cols tx*4 .. +3
    const int ty = tid >> 5;   // token group: rows ty*8 .. +7

    float acc[8][4];
#pragma unroll
    for (int i = 0; i < 8; i++)
#pragma unroll
        for (int j = 0; j < 4; j++) acc[i][j] = 0.f;

    // x staging: thread -> (token, kvec)
    const int xtok = tid >> 2;        // 0..63
    const int xkv  = (tid & 3) * 4;   // 0,4,8,12
    const float* xg = x + (size_t)(t0 + xtok) * DM + xkv;

    // W1 staging: 512 float4 per chunk, 2 per thread
    const int kk0 = tid >> 5, nv0 = (tid & 31) * 4;
    const int j1 = tid + 256;
    const int kk1 = j1 >> 5, nv1 = (j1 & 31) * 4;

    for (int k0 = 0; k0 < DM; k0 += 16) {
        float4 xv = *(const float4*)(xg + k0);
        float4 wv0 = *(const float4*)(W1 + (size_t)(k0 + kk0) * DH + n0 + nv0);
        float4 wv1 = *(const float4*)(W1 + (size_t)(k0 + kk1) * DH + n0 + nv1);
        __syncthreads();   // protect LDS from previous iteration's readers
        xs[xkv + 0][xtok] = xv.x;
        xs[xkv + 1][xtok] = xv.y;
        xs[xkv + 2][xtok] = xv.z;
        xs[xkv + 3][xtok] = xv.w;
        *(float4*)&ws[kk0][nv0] = wv0;
        *(float4*)&ws[kk1][nv1] = wv1;
        __syncthreads();
#pragma unroll
        for (int kk = 0; kk < 16; kk++) {
            float4 b = *(const float4*)&ws[kk][tx * 4];
            float4 a0 = *(const float4*)&xs[kk][ty * 8];
            float4 a1 = *(const float4*)&xs[kk][ty * 8 + 4];
            float a[8] = {a0.x, a0.y, a0.z, a0.w, a1.x, a1.y, a1.z, a1.w};
#pragma unroll
            for (int i = 0; i < 8; i++) {
                acc[i][0] += a[i] * b.x;
                acc[i][1] += a[i] * b.y;
                acc[i][2] += a[i] * b.z;
                acc[i][3] += a[i] * b.w;
            }
        }
    }

    float4 bb = *(const float4*)(b1 + n0 + tx * 4);
#pragma unroll
    for (int i = 0; i < 8; i++) {
        float4 o;
        o.x = tanhf(acc[i][0] + bb.x);
        o.y = tanhf(acc[i][1] + bb.y);
        o.z = tanhf(acc[i][2] + bb.z);
        o.w = tanhf(acc[i][3] + bb.w);
        *(float4*)(h + (size_t)(t0 + ty * 8 + i) * DH + n0 + tx * 4) = o;
    }
}

// ---------------- GEMM2 + top-2 softmax gating ----------------
// block = 256 threads, 64 tokens per block. grid: T/64.
__global__ __launch_bounds__(256, 1)
void gate_kernel(const float* __restrict__ h, const float* __restrict__ W2,
                 const float* __restrict__ b2, float* __restrict__ gates,
                 float* __restrict__ logits_out) {
    __shared__ float hs[16][68];    // hs[k][tok] per chunk
    __shared__ float w2s[DH][NE];   // full W2, 64 KB
    __shared__ float ls[64][68];    // logits tile [tok][e], padded for 16B-aligned rows

    const int tid = threadIdx.x;
    const int t0 = blockIdx.x * 64;
    const int tx = tid & 15;   // expert group: e = tx*4..+3
    const int ty = tid >> 4;   // token group: tok = ty*4..+3

    // load full W2 (coalesced): 4096 float4, 16 per thread
#pragma unroll
    for (int r = 0; r < 16; r++) {
        int j = tid + r * 256;       // 0..4095
        int k = j >> 4;              // 0..255
        int ev = (j & 15) * 4;
        *(float4*)&w2s[k][ev] = *(const float4*)(W2 + k * NE + ev);
    }

    float acc[4][4];
#pragma unroll
    for (int i = 0; i < 4; i++)
#pragma unroll
        for (int j = 0; j < 4; j++) acc[i][j] = 0.f;

    const int htok = tid >> 2;
    const int hkv  = (tid & 3) * 4;
    const float* hg = h + (size_t)(t0 + htok) * DH + hkv;

    for (int k0 = 0; k0 < DH; k0 += 16) {
        float4 hv = *(const float4*)(hg + k0);
        __syncthreads();   // also covers the initial w2s fill on first iteration
        hs[hkv + 0][htok] = hv.x;
        hs[hkv + 1][htok] = hv.y;
        hs[hkv + 2][htok] = hv.z;
        hs[hkv + 3][htok] = hv.w;
        __syncthreads();
#pragma unroll
        for (int kk = 0; kk < 16; kk++) {
            float4 a = *(const float4*)&hs[kk][ty * 4];
            float4 b = *(const float4*)&w2s[k0 + kk][tx * 4];
            float av[4] = {a.x, a.y, a.z, a.w};
#pragma unroll
            for (int i = 0; i < 4; i++) {
                acc[i][0] += av[i] * b.x;
                acc[i][1] += av[i] * b.y;
                acc[i][2] += av[i] * b.z;
                acc[i][3] += av[i] * b.w;
            }
        }
    }

    // stash logits tile (without b2; added per-lane below)
#pragma unroll
    for (int i = 0; i < 4; i++) {
        float4 o = {acc[i][0], acc[i][1], acc[i][2], acc[i][3]};
        *(float4*)&ls[ty * 4 + i][tx * 4] = o;
    }
    __syncthreads();

    // gating: 4 waves x 16 tokens; lane = expert
    const int wave = tid >> 6;
    const int lane = tid & 63;
    const float b2v = b2[lane];

    for (int t = 0; t < 16; t++) {
        const int tok = wave * 16 + t;
        const float lg = ls[tok][lane] + b2v;

        // top-1 (lower index wins ties, matching jax.lax.top_k)
        float m1 = lg; int i1 = lane;
#pragma unroll
        for (int off = 32; off; off >>= 1) {
            float om = __shfl_xor(m1, off, 64);
            int oi = __shfl_xor(i1, off, 64);
            if (om > m1 || (om == m1 && oi < i1)) { m1 = om; i1 = oi; }
        }
        // top-2
        float l2 = (lane == i1) ? -INFINITY : lg;
        float m2 = l2; int i2 = lane;
#pragma unroll
        for (int off = 32; off; off >>= 1) {
            float om = __shfl_xor(m2, off, 64);
            int oi = __shfl_xor(i2, off, 64);
            if (om > m2 || (om == m2 && oi < i2)) { m2 = om; i2 = oi; }
        }
        // softmax over [m1, m2]; m2 <= m1 so stable
        float e = __expf(m2 - m1);
        float inv = 1.f / (1.f + e);
        float g1 = inv, g2 = e * inv;

        float g = (lane == i1) ? g1 : ((lane == i2) ? g2 : 0.f);
        size_t row = (size_t)(t0 + tok) * NE;
        gates[row + lane] = g;
        logits_out[row + lane] = lg;
    }
}

extern "C" void kernel_launch(void* const* d_in, const int* in_sizes, int n_in,
                              void* d_out, int out_size, void* d_ws, size_t ws_size,
                              hipStream_t stream) {
    const float* x  = (const float*)d_in[0];
    const float* W1 = (const float*)d_in[1];
    const float* b1 = (const float*)d_in[2];
    const float* W2 = (const float*)d_in[3];
    const float* b2 = (const float*)d_in[4];

    const int T = in_sizes[0] / DM;   // 16384
    float* h = (float*)d_ws;          // T*256 floats = 16.78 MB scratch
    float* gates = (float*)d_out;
    float* logits = (float*)d_out + (size_t)T * NE;

    dim3 blk(256);
    dim3 g1(T / 64, 2);
    gemm1_kernel<<<g1, blk, 0, stream>>>(x, W1, b1, h);
    gate_kernel<<<T / 64, blk, 0, stream>>>(h, W2, b2, gates, logits);
}